// Round 1
// baseline (258.823 us; speedup 1.0000x reference)
//
#include <hip/hip_runtime.h>
#include <hip/hip_bf16.h>

// Problem dims (fixed by reference)
#define L_DIM 2048
#define B_DIM 8
#define D_DIM 1024
#define M_DIM (L_DIM * B_DIM)   // 16384 rows of x_norm
#define N_DIM (3 * D_DIM)       // 3072
#define K_DIM D_DIM             // 1024
#define BD (B_DIM * D_DIM)      // 8192 independent recurrence chains
#define NCHUNK 64
#define CLEN (L_DIM / NCHUNK)   // 32

typedef __attribute__((ext_vector_type(8))) __bf16 bf16x8;
typedef __attribute__((ext_vector_type(4))) __bf16 bf16x4;
typedef __attribute__((ext_vector_type(4))) float f32x4;

#define GLOAD_LDS16(g, l)                                        \
  __builtin_amdgcn_global_load_lds(                              \
      (const __attribute__((address_space(1))) void*)(g),        \
      (__attribute__((address_space(3))) void*)(l), 16, 0, 0)

__device__ __forceinline__ float sigmoidf_(float v) {
  return 1.0f / (1.0f + __expf(-v));
}

// ---------------------------------------------------------------------------
// Kernel 1: LayerNorm per (l,b) row of D=1024. One block per row, 256 thr,
// float4 per thread. Output bf16 (feeds MFMA GEMM and the hs blend).
// ---------------------------------------------------------------------------
__global__ __launch_bounds__(256) void ln_kernel(
    const float* __restrict__ x, const float* __restrict__ gamma,
    const float* __restrict__ beta, __bf16* __restrict__ xn) {
  const int row = blockIdx.x;          // l*B + b
  const int tid = threadIdx.x;
  const float4 v = ((const float4*)(x + (size_t)row * D_DIM))[tid];
  float s  = v.x + v.y + v.z + v.w;
  float ss = v.x * v.x + v.y * v.y + v.z * v.z + v.w * v.w;
  // 64-lane butterfly
  #pragma unroll
  for (int off = 32; off > 0; off >>= 1) {
    s  += __shfl_xor(s, off);
    ss += __shfl_xor(ss, off);
  }
  __shared__ float sb[8];
  const int wid = tid >> 6, lane = tid & 63;
  if (lane == 0) { sb[wid] = s; sb[4 + wid] = ss; }
  __syncthreads();
  const float tot  = sb[0] + sb[1] + sb[2] + sb[3];
  const float tot2 = sb[4] + sb[5] + sb[6] + sb[7];
  const float mu  = tot * (1.0f / D_DIM);
  const float var = tot2 * (1.0f / D_DIM) - mu * mu;
  const float rstd = rsqrtf(var + 1e-5f);
  const float4 g  = ((const float4*)gamma)[tid];
  const float4 bt = ((const float4*)beta)[tid];
  bf16x4 o;
  o[0] = (__bf16)((v.x - mu) * rstd * g.x + bt.x);
  o[1] = (__bf16)((v.y - mu) * rstd * g.y + bt.y);
  o[2] = (__bf16)((v.z - mu) * rstd * g.z + bt.z);
  o[3] = (__bf16)((v.w - mu) * rstd * g.w + bt.w);
  ((bf16x4*)(xn + (size_t)row * D_DIM))[tid] = o;
}

// ---------------------------------------------------------------------------
// Kernel 2: W fp32 -> bf16 (W is [3D][D], K-contiguous = B^T layout for GEMM)
// ---------------------------------------------------------------------------
__global__ __launch_bounds__(256) void wconv_kernel(
    const float* __restrict__ W, __bf16* __restrict__ Wb) {
  const size_t i = ((size_t)blockIdx.x * 256 + threadIdx.x) * 4;
  const float4 v = *(const float4*)(W + i);
  bf16x4 o;
  o[0] = (__bf16)v.x; o[1] = (__bf16)v.y; o[2] = (__bf16)v.z; o[3] = (__bf16)v.w;
  *(bf16x4*)(Wb + i) = o;
}

// ---------------------------------------------------------------------------
// Kernel 3: GEMM  C[m,e] = sum_d xn[m,d] * W[e,d] + b[e], fused sigmoid for
// the f/r thirds. m97 structure: 128x128 tile, BK=64, 4 waves (2x2), each
// wave 64x64 via 4x4 frags of mfma_f32_16x16x32_bf16, global_load_lds w=16.
// ---------------------------------------------------------------------------
__global__ __launch_bounds__(256) void gemm_kernel(
    const __bf16* __restrict__ A,   // [M][K] x_norm bf16
    const __bf16* __restrict__ Bm,  // [N][K] W bf16 (B^T layout)
    const float* __restrict__ bias, // [3072]
    __bf16* __restrict__ U, __bf16* __restrict__ FG, __bf16* __restrict__ RG) {
  __shared__ __bf16 As[128 * 64];
  __shared__ __bf16 Bs[128 * 64];
  const int tid = threadIdx.x;
  const int lane = tid & 63;
  const int wid = tid >> 6;
  const int wm = wid >> 1, wn = wid & 1;
  const int bm = blockIdx.x, bn = blockIdx.y;

  f32x4 acc[4][4] = {};

  const __bf16* Agbase = A + (size_t)(bm * 128) * K_DIM;
  const __bf16* Bgbase = Bm + (size_t)(bn * 128) * K_DIM;

  for (int kt = 0; kt < K_DIM / 64; ++kt) {
    __syncthreads();  // previous compute done before overwriting tiles
    #pragma unroll
    for (int it = 0; it < 4; ++it) {
      const int ci = it * 256 + tid;       // 16B chunk index in tile
      const int row = ci >> 3, c8 = ci & 7;
      const size_t goff = (size_t)row * K_DIM + kt * 64 + c8 * 8;
      GLOAD_LDS16(Agbase + goff, As + (size_t)ci * 8);
      GLOAD_LDS16(Bgbase + goff, Bs + (size_t)ci * 8);
    }
    __syncthreads();  // implies s_waitcnt vmcnt(0): tiles visible
    #pragma unroll
    for (int ks = 0; ks < 2; ++ks) {
      const int kof = ks * 32 + (lane >> 4) * 8;  // k = (lane/16)*8 + i
      bf16x8 af[4], bf[4];
      #pragma unroll
      for (int fm = 0; fm < 4; ++fm) {
        const int r = wm * 64 + fm * 16 + (lane & 15);
        af[fm] = *(const bf16x8*)(As + r * 64 + kof);
      }
      #pragma unroll
      for (int fn = 0; fn < 4; ++fn) {
        const int r = wn * 64 + fn * 16 + (lane & 15);
        bf[fn] = *(const bf16x8*)(Bs + r * 64 + kof);
      }
      #pragma unroll
      for (int fm = 0; fm < 4; ++fm)
        #pragma unroll
        for (int fn = 0; fn < 4; ++fn)
          acc[fm][fn] = __builtin_amdgcn_mfma_f32_16x16x32_bf16(
              af[fm], bf[fn], acc[fm][fn], 0, 0, 0);
    }
  }

  // Epilogue. Each 128-wide N-tile lies wholly inside one of {u, f, r}.
  const int seg = (bn * 128) >> 10;            // 0:u 1:f 2:r
  const int nbase = (bn * 128) & 1023;
  __bf16* outb = (seg == 0) ? U : ((seg == 1) ? FG : RG);
  const int ccol = lane & 15;
  const int crow = (lane >> 4) * 4;            // C/D: col=lane&15, row=(lane>>4)*4+j
  #pragma unroll
  for (int fm = 0; fm < 4; ++fm) {
    #pragma unroll
    for (int fn = 0; fn < 4; ++fn) {
      const int ng = bn * 128 + wn * 64 + fn * 16 + ccol;
      const float bv = bias[ng];
      const int nl = nbase + wn * 64 + fn * 16 + ccol;
      const int m0 = bm * 128 + wm * 64 + fm * 16 + crow;
      #pragma unroll
      for (int j = 0; j < 4; ++j) {
        float v = acc[fm][fn][j] + bv;
        if (seg != 0) v = sigmoidf_(v);
        outb[(size_t)(m0 + j) * D_DIM + nl] = (__bf16)v;
      }
    }
  }
}

// ---------------------------------------------------------------------------
// Scan pass A: per (chunk, bd) compute affine composition c_out = a*c_in + v
// over CLEN steps.  av[0..NCHUNK*BD) = a,  av[NCHUNK*BD..) = v.
// ---------------------------------------------------------------------------
__global__ __launch_bounds__(256) void scanA_kernel(
    const __bf16* __restrict__ fg, const __bf16* __restrict__ u,
    float* __restrict__ av) {
  const int ci = blockIdx.x;
  const int bd = blockIdx.y * 256 + threadIdx.x;
  float a = 1.0f, v = 0.0f;
  const size_t base = (size_t)ci * CLEN * BD + bd;
  #pragma unroll 8
  for (int i = 0; i < CLEN; ++i) {
    const size_t idx = base + (size_t)i * BD;
    const float f = (float)fg[idx];
    const float uu = (float)u[idx];
    a *= f;
    v = f * v + (1.0f - f) * uu;
  }
  av[(size_t)ci * BD + bd] = a;
  av[(size_t)NCHUNK * BD + (size_t)ci * BD + bd] = v;
}

// ---------------------------------------------------------------------------
// Scan pass B: sequential combine across chunks (tiny: 8192 threads x 64).
// carries[ci] = c entering chunk ci; also writes last_c output.
// ---------------------------------------------------------------------------
__global__ __launch_bounds__(256) void scanB_kernel(
    const float* __restrict__ av, const float* __restrict__ c0,
    float* __restrict__ carries, float* __restrict__ out1) {
  const int bd = blockIdx.x * 256 + threadIdx.x;
  float c = c0[bd];
  #pragma unroll 8
  for (int ci = 0; ci < NCHUNK; ++ci) {
    carries[(size_t)ci * BD + bd] = c;
    c = av[(size_t)ci * BD + bd] * c + av[(size_t)NCHUNK * BD + (size_t)ci * BD + bd];
  }
  out1[bd] = c;
}

// ---------------------------------------------------------------------------
// Scan pass C: re-run recurrence within chunk from the correct carry, fuse
// hs = r*tanh(c) + (1-r)*xn and residual add; write final output.
// ---------------------------------------------------------------------------
__global__ __launch_bounds__(256) void scanC_kernel(
    const __bf16* __restrict__ fg, const __bf16* __restrict__ u,
    const __bf16* __restrict__ rg, const __bf16* __restrict__ xn,
    const float* __restrict__ x, const float* __restrict__ carries,
    float* __restrict__ out0) {
  const int ci = blockIdx.x;
  const int bd = blockIdx.y * 256 + threadIdx.x;
  float c = carries[(size_t)ci * BD + bd];
  const size_t base = (size_t)ci * CLEN * BD + bd;
  #pragma unroll 4
  for (int i = 0; i < CLEN; ++i) {
    const size_t idx = base + (size_t)i * BD;
    const float f = (float)fg[idx];
    const float uu = (float)u[idx];
    c = f * c + (1.0f - f) * uu;
    const float r = (float)rg[idx];
    const float xnv = (float)xn[idx];
    const float hs = r * tanhf(c) + (1.0f - r) * xnv;
    out0[idx] = x[idx] + hs;
  }
}

// ---------------------------------------------------------------------------
extern "C" void kernel_launch(void* const* d_in, const int* in_sizes, int n_in,
                              void* d_out, int out_size, void* d_ws,
                              size_t ws_size, hipStream_t stream) {
  const float* x     = (const float*)d_in[0];  // [L,B,D]
  const float* c0    = (const float*)d_in[1];  // [B,D]
  const float* W     = (const float*)d_in[2];  // [3D,D]
  const float* bias  = (const float*)d_in[3];  // [3D]
  const float* gamma = (const float*)d_in[4];  // [D]
  const float* beta  = (const float*)d_in[5];  // [D]

  float* out0 = (float*)d_out;                       // [L,B,D]
  float* out1 = out0 + (size_t)M_DIM * D_DIM;        // [B,D]

  // Workspace layout (bytes), all 4 KB-aligned:
  char* ws = (char*)d_ws;
  __bf16* xn = (__bf16*)(ws + 0);                          // 32 MB
  __bf16* Wb = (__bf16*)(ws + 33554432);                   //  6 MB
  __bf16* U  = (__bf16*)(ws + 39845888);                   // 32 MB
  __bf16* FG = (__bf16*)(ws + 73400320);                   // 32 MB
  __bf16* RG = (__bf16*)(ws + 106954752);                  // 32 MB
  float* av      = (float*)(ws + 140509184);               //  4 MB
  float* carries = (float*)(ws + 144703488);               //  2 MB
  // total: ~140 MB

  ln_kernel<<<M_DIM, 256, 0, stream>>>(x, gamma, beta, xn);
  wconv_kernel<<<(N_DIM * K_DIM / 4) / 256, 256, 0, stream>>>(W, Wb);
  gemm_kernel<<<dim3(M_DIM / 128, N_DIM / 128), 256, 0, stream>>>(
      xn, Wb, bias, U, FG, RG);
  scanA_kernel<<<dim3(NCHUNK, BD / 256), 256, 0, stream>>>(FG, U, av);
  scanB_kernel<<<BD / 256, 256, 0, stream>>>(av, c0, carries, out1);
  scanC_kernel<<<dim3(NCHUNK, BD / 256), 256, 0, stream>>>(
      FG, U, RG, xn, x, carries, out0);
}

// Round 2
// 241.603 us; speedup vs baseline: 1.0713x; 1.0713x over previous
//
#include <hip/hip_runtime.h>
#include <hip/hip_bf16.h>

// Problem dims (fixed by reference)
#define L_DIM 2048
#define B_DIM 8
#define D_DIM 1024
#define M_DIM (L_DIM * B_DIM)   // 16384 rows of x_norm
#define N_DIM (3 * D_DIM)       // 3072
#define K_DIM D_DIM             // 1024
#define BD (B_DIM * D_DIM)      // 8192 independent recurrence chains
#define NCHUNK 64
#define CLEN (L_DIM / NCHUNK)   // 32

typedef __attribute__((ext_vector_type(8))) __bf16 bf16x8;
typedef __attribute__((ext_vector_type(4))) __bf16 bf16x4;
typedef __attribute__((ext_vector_type(4))) float f32x4;

#define GLOAD_LDS16(g, l)                                        \
  __builtin_amdgcn_global_load_lds(                              \
      (const __attribute__((address_space(1))) void*)(g),        \
      (__attribute__((address_space(3))) void*)(l), 16, 0, 0)

__device__ __forceinline__ float sigmoidf_(float v) {
  return 1.0f / (1.0f + __expf(-v));
}

// ---------------------------------------------------------------------------
// Kernel 1: LayerNorm per (l,b) row of D=1024.
// ---------------------------------------------------------------------------
__global__ __launch_bounds__(256) void ln_kernel(
    const float* __restrict__ x, const float* __restrict__ gamma,
    const float* __restrict__ beta, __bf16* __restrict__ xn) {
  const int row = blockIdx.x;
  const int tid = threadIdx.x;
  const float4 v = ((const float4*)(x + (size_t)row * D_DIM))[tid];
  float s  = v.x + v.y + v.z + v.w;
  float ss = v.x * v.x + v.y * v.y + v.z * v.z + v.w * v.w;
  #pragma unroll
  for (int off = 32; off > 0; off >>= 1) {
    s  += __shfl_xor(s, off);
    ss += __shfl_xor(ss, off);
  }
  __shared__ float sb[8];
  const int wid = tid >> 6, lane = tid & 63;
  if (lane == 0) { sb[wid] = s; sb[4 + wid] = ss; }
  __syncthreads();
  const float tot  = sb[0] + sb[1] + sb[2] + sb[3];
  const float tot2 = sb[4] + sb[5] + sb[6] + sb[7];
  const float mu  = tot * (1.0f / D_DIM);
  const float var = tot2 * (1.0f / D_DIM) - mu * mu;
  const float rstd = rsqrtf(var + 1e-5f);
  const float4 g  = ((const float4*)gamma)[tid];
  const float4 bt = ((const float4*)beta)[tid];
  bf16x4 o;
  o[0] = (__bf16)((v.x - mu) * rstd * g.x + bt.x);
  o[1] = (__bf16)((v.y - mu) * rstd * g.y + bt.y);
  o[2] = (__bf16)((v.z - mu) * rstd * g.z + bt.z);
  o[3] = (__bf16)((v.w - mu) * rstd * g.w + bt.w);
  ((bf16x4*)(xn + (size_t)row * D_DIM))[tid] = o;
}

// ---------------------------------------------------------------------------
// Kernel 2: W fp32 -> bf16
// ---------------------------------------------------------------------------
__global__ __launch_bounds__(256) void wconv_kernel(
    const float* __restrict__ W, __bf16* __restrict__ Wb) {
  const size_t i = ((size_t)blockIdx.x * 256 + threadIdx.x) * 4;
  const float4 v = *(const float4*)(W + i);
  bf16x4 o;
  o[0] = (__bf16)v.x; o[1] = (__bf16)v.y; o[2] = (__bf16)v.z; o[3] = (__bf16)v.w;
  *(bf16x4*)(Wb + i) = o;
}

// ---------------------------------------------------------------------------
// Kernel 3: 256x256-tile GEMM, 4-phase counted-vmcnt pipeline (T3+T4+T5+T1).
//
// Geometry: BK=64, 8 waves (wm 0..1 x wn 0..3), per-wave 128x64 output =
// acc[8][4] f32x4.  LDS 128 KiB = 2 buffers x {A 32K, B 32K}.
// Stage unit = (op, row-half, K-half) = 8 KB, layout [kg(4)][row(128)][16B]
// (conflict-free ds_read_b128 by construction). Unit staged by its 4 reader
// waves (A[h][*] by waves wm==h, kg=wn; B[g][*] by waves wn>>1==g,
// kg=wm*2+(wn&1)) -> per-wave vmcnt counts only units that wave reads.
//
// Issue schedule (per tile t, 1 unit = 2 loads/thread per phase):
//   P1: A[K1](t+1)   P2: B[K1](t+1)   P3: A[K0](t+2)   P4: B[K0](t+2)
// Slot safety: A/B[K0] of buf(t%2) last read at t.P2 (ks0 phases); re-issued
// at t.P3/P4 after the P2-end barrier. K1 slots of buf(t+1 %2) last read at
// (t-1).P3/P4. All issue points are after the last-read barrier. 
// Consume guarantees (per-wave, pairs newest-first at each wait):
//   t.P2-end vmcnt(8): K1(t) [issued (t-1).P1/P2] older than newest 4 pairs.
//   t.P4-end vmcnt(8): K0(t+1) [issued (t-1).P3/P4] older than newest 4.
// Tail: t=14.P4 -> vmcnt(4); t=15.P2 -> vmcnt(0); t=15.P4 -> none.
// Prologue: stage t0{AK0,BK0,AK1,BK1}, t1{AK0,BK0}; vmcnt(4); barrier.
// ---------------------------------------------------------------------------
#define VMCNT(n) asm volatile("s_waitcnt vmcnt(" #n ")" ::: "memory")

__global__ __launch_bounds__(512, 2) void gemm256_kernel(
    const __bf16* __restrict__ A,   // [M][K]
    const __bf16* __restrict__ Bm,  // [N][K]
    const float* __restrict__ bias,
    __bf16* __restrict__ U, __bf16* __restrict__ FG, __bf16* __restrict__ RG) {
  __shared__ __bf16 lds[65536];  // 128 KiB
  const int tid = threadIdx.x;
  const int lane = tid & 63;
  const int wid = tid >> 6;       // 0..7
  const int wm = wid >> 2;        // 0..1  (row-half)
  const int wn = wid & 3;         // 0..3  (col quarter)
  const int g  = wn >> 1;         // B row-half this wave reads

  // XCD-bijective swizzle: 768 blocks, 768 % 8 == 0.
  const int bid0 = blockIdx.x;
  const int bid = (bid0 & 7) * 96 + (bid0 >> 3);
  const int bm = bid / 12, bn = bid % 12;

  const int arow0 = bm * 256 + wm * 128;   // A rows this wave stages/reads
  const int brow0 = bn * 256 + g * 128;    // B rows this wave stages/reads
  const int akg = wn;                      // kg this wave stages for A units
  const int bkg = wm * 2 + (wn & 1);       // kg this wave stages for B units

  // LDS element offsets (bf16 units). Unit = 4096 elems (8 KB).
  // Buffer: A[half][ks] at 0..16383, B[g][ks] at 16384..32767.
#define AUNIT(buf, half, ks) ((buf) * 32768 + (half) * 8192 + (ks) * 4096)
#define BUNIT(buf, gg, ks)   ((buf) * 32768 + 16384 + (gg) * 8192 + (ks) * 4096)

  // Stage A[wm][ks] of tile kt2 (kg=akg): rows r=lane and r=lane+64.
  auto stageA = [&](int kt2, int ks) {
    const int buf = kt2 & 1;
    const __bf16* gs = A + (size_t)arow0 * K_DIM + kt2 * 64 + ks * 32 + akg * 8;
    __bf16* ls = lds + AUNIT(buf, wm, ks) + akg * 1024;
    GLOAD_LDS16(gs + (size_t)lane * K_DIM, ls + lane * 8);
    GLOAD_LDS16(gs + (size_t)(lane + 64) * K_DIM, ls + (lane + 64) * 8);
  };
  auto stageB = [&](int kt2, int ks) {
    const int buf = kt2 & 1;
    const __bf16* gs = Bm + (size_t)brow0 * K_DIM + kt2 * 64 + ks * 32 + bkg * 8;
    __bf16* ls = lds + BUNIT(buf, g, ks) + bkg * 1024;
    GLOAD_LDS16(gs + (size_t)lane * K_DIM, ls + lane * 8);
    GLOAD_LDS16(gs + (size_t)(lane + 64) * K_DIM, ls + (lane + 64) * 8);
  };

  const int fr = lane & 15, fk = lane >> 4;
  // Frag reads: lane -> (kg=fk, row), 16B contiguous -> conflict-free.
  auto rdA = [&](int buf, int ks, int m) {
    return *(const bf16x8*)(lds + AUNIT(buf, wm, ks) + fk * 1024 +
                            (m * 16 + fr) * 8);
  };
  auto rdB = [&](int buf, int ks, int n) {
    return *(const bf16x8*)(lds + BUNIT(buf, g, ks) + fk * 1024 +
                            ((wn & 1) * 64 + n * 16 + fr) * 8);
  };

  f32x4 acc[8][4] = {};

  // Prologue: tile0 all 4 units, tile1 K0 units. vmcnt(4) keeps tile1-K0
  // (2 newest pairs) in flight; tile0 fully landed.
  stageA(0, 0); stageB(0, 0); stageA(0, 1); stageB(0, 1);
  stageA(1, 0); stageB(1, 0);
  VMCNT(4);
  __builtin_amdgcn_s_barrier();

  #pragma unroll 1
  for (int kt = 0; kt < 16; ++kt) {
    const int buf = kt & 1;
    bf16x8 a[4], b[4];

    // ---- P1: ks0, m 0-3 ----
    #pragma unroll
    for (int m = 0; m < 4; ++m) a[m] = rdA(buf, 0, m);
    #pragma unroll
    for (int n = 0; n < 4; ++n) b[n] = rdB(buf, 0, n);
    if (kt < 15) stageA(kt + 1, 1);
    __builtin_amdgcn_s_barrier();
    __builtin_amdgcn_s_setprio(1);
    #pragma unroll
    for (int m = 0; m < 4; ++m)
      #pragma unroll
      for (int n = 0; n < 4; ++n)
        acc[m][n] = __builtin_amdgcn_mfma_f32_16x16x32_bf16(a[m], b[n],
                                                            acc[m][n], 0, 0, 0);
    __builtin_amdgcn_s_setprio(0);
    __builtin_amdgcn_s_barrier();

    // ---- P2: ks0, m 4-7 ----
    #pragma unroll
    for (int m = 0; m < 4; ++m) a[m] = rdA(buf, 0, m + 4);
    if (kt < 15) stageB(kt + 1, 1);
    __builtin_amdgcn_s_barrier();
    __builtin_amdgcn_s_setprio(1);
    #pragma unroll
    for (int m = 0; m < 4; ++m)
      #pragma unroll
      for (int n = 0; n < 4; ++n)
        acc[m + 4][n] = __builtin_amdgcn_mfma_f32_16x16x32_bf16(
            a[m], b[n], acc[m + 4][n], 0, 0, 0);
    __builtin_amdgcn_s_setprio(0);
    if (kt == 15) { VMCNT(0); } else { VMCNT(8); }  // K1(kt) guaranteed
    __builtin_amdgcn_s_barrier();

    // ---- P3: ks1, m 0-3 ----
    #pragma unroll
    for (int m = 0; m < 4; ++m) a[m] = rdA(buf, 1, m);
    #pragma unroll
    for (int n = 0; n < 4; ++n) b[n] = rdB(buf, 1, n);
    if (kt < 14) stageA(kt + 2, 0);
    __builtin_amdgcn_s_barrier();
    __builtin_amdgcn_s_setprio(1);
    #pragma unroll
    for (int m = 0; m < 4; ++m)
      #pragma unroll
      for (int n = 0; n < 4; ++n)
        acc[m][n] = __builtin_amdgcn_mfma_f32_16x16x32_bf16(a[m], b[n],
                                                            acc[m][n], 0, 0, 0);
    __builtin_amdgcn_s_setprio(0);
    __builtin_amdgcn_s_barrier();

    // ---- P4: ks1, m 4-7 ----
    #pragma unroll
    for (int m = 0; m < 4; ++m) a[m] = rdA(buf, 1, m + 4);
    if (kt < 14) stageB(kt + 2, 0);
    __builtin_amdgcn_s_barrier();
    __builtin_amdgcn_s_setprio(1);
    #pragma unroll
    for (int m = 0; m < 4; ++m)
      #pragma unroll
      for (int n = 0; n < 4; ++n)
        acc[m + 4][n] = __builtin_amdgcn_mfma_f32_16x16x32_bf16(
            a[m], b[n], acc[m + 4][n], 0, 0, 0);
    __builtin_amdgcn_s_setprio(0);
    if (kt < 14) { VMCNT(8); }            // K0(kt+1) guaranteed
    else if (kt == 14) { VMCNT(4); }      // tail: only K1(15) may stay out
    __builtin_amdgcn_s_barrier();
  }

  // Epilogue: bias + (sigmoid for f/r) + bf16 store.
  const int seg = bn >> 2;  // 0:u 1:f 2:r (256-wide tiles lie in one segment)
  __bf16* outb = (seg == 0) ? U : ((seg == 1) ? FG : RG);
  const int nl0 = (bn & 3) * 256 + wn * 64;
  const int m00 = bm * 256 + wm * 128;
  #pragma unroll
  for (int n = 0; n < 4; ++n) {
    const int col = nl0 + n * 16 + fr;
    const float bv = bias[seg * 1024 + col];
    #pragma unroll
    for (int m = 0; m < 8; ++m) {
      const int r0 = m00 + m * 16 + fk * 4;
      #pragma unroll
      for (int j = 0; j < 4; ++j) {
        float v = acc[m][n][j] + bv;
        if (seg != 0) v = sigmoidf_(v);
        outb[(size_t)(r0 + j) * D_DIM + col] = (__bf16)v;
      }
    }
  }
}

// ---------------------------------------------------------------------------
// Scan pass A: per (chunk, bd) affine composition over CLEN steps.
// ---------------------------------------------------------------------------
__global__ __launch_bounds__(256) void scanA_kernel(
    const __bf16* __restrict__ fg, const __bf16* __restrict__ u,
    float* __restrict__ av) {
  const int ci = blockIdx.x;
  const int bd = blockIdx.y * 256 + threadIdx.x;
  float a = 1.0f, v = 0.0f;
  const size_t base = (size_t)ci * CLEN * BD + bd;
  #pragma unroll 8
  for (int i = 0; i < CLEN; ++i) {
    const size_t idx = base + (size_t)i * BD;
    const float f = (float)fg[idx];
    const float uu = (float)u[idx];
    a *= f;
    v = f * v + (1.0f - f) * uu;
  }
  av[(size_t)ci * BD + bd] = a;
  av[(size_t)NCHUNK * BD + (size_t)ci * BD + bd] = v;
}

// ---------------------------------------------------------------------------
// Scan pass B: sequential combine across chunks; writes last_c.
// ---------------------------------------------------------------------------
__global__ __launch_bounds__(256) void scanB_kernel(
    const float* __restrict__ av, const float* __restrict__ c0,
    float* __restrict__ carries, float* __restrict__ out1) {
  const int bd = blockIdx.x * 256 + threadIdx.x;
  float c = c0[bd];
  #pragma unroll 8
  for (int ci = 0; ci < NCHUNK; ++ci) {
    carries[(size_t)ci * BD + bd] = c;
    c = av[(size_t)ci * BD + bd] * c + av[(size_t)NCHUNK * BD + (size_t)ci * BD + bd];
  }
  out1[bd] = c;
}

// ---------------------------------------------------------------------------
// Scan pass C: re-run recurrence within chunk, fuse hs + residual.
// ---------------------------------------------------------------------------
__global__ __launch_bounds__(256) void scanC_kernel(
    const __bf16* __restrict__ fg, const __bf16* __restrict__ u,
    const __bf16* __restrict__ rg, const __bf16* __restrict__ xn,
    const float* __restrict__ x, const float* __restrict__ carries,
    float* __restrict__ out0) {
  const int ci = blockIdx.x;
  const int bd = blockIdx.y * 256 + threadIdx.x;
  float c = carries[(size_t)ci * BD + bd];
  const size_t base = (size_t)ci * CLEN * BD + bd;
  #pragma unroll 4
  for (int i = 0; i < CLEN; ++i) {
    const size_t idx = base + (size_t)i * BD;
    const float f = (float)fg[idx];
    const float uu = (float)u[idx];
    c = f * c + (1.0f - f) * uu;
    const float r = (float)rg[idx];
    const float xnv = (float)xn[idx];
    const float hs = r * tanhf(c) + (1.0f - r) * xnv;
    out0[idx] = x[idx] + hs;
  }
}

// ---------------------------------------------------------------------------
extern "C" void kernel_launch(void* const* d_in, const int* in_sizes, int n_in,
                              void* d_out, int out_size, void* d_ws,
                              size_t ws_size, hipStream_t stream) {
  const float* x     = (const float*)d_in[0];
  const float* c0    = (const float*)d_in[1];
  const float* W     = (const float*)d_in[2];
  const float* bias  = (const float*)d_in[3];
  const float* gamma = (const float*)d_in[4];
  const float* beta  = (const float*)d_in[5];

  float* out0 = (float*)d_out;                 // [L,B,D]
  float* out1 = out0 + (size_t)M_DIM * D_DIM;  // [B,D]

  char* ws = (char*)d_ws;
  __bf16* xn = (__bf16*)(ws + 0);              // 32 MB
  __bf16* Wb = (__bf16*)(ws + 33554432);       //  6 MB
  __bf16* U  = (__bf16*)(ws + 39845888);       // 32 MB
  __bf16* FG = (__bf16*)(ws + 73400320);       // 32 MB
  __bf16* RG = (__bf16*)(ws + 106954752);      // 32 MB
  float* av      = (float*)(ws + 140509184);   //  4 MB
  float* carries = (float*)(ws + 144703488);   //  2 MB

  ln_kernel<<<M_DIM, 256, 0, stream>>>(x, gamma, beta, xn);
  wconv_kernel<<<(N_DIM * K_DIM / 4) / 256, 256, 0, stream>>>(W, Wb);
  gemm256_kernel<<<(M_DIM / 256) * (N_DIM / 256), 512, 0, stream>>>(
      xn, Wb, bias, U, FG, RG);
  scanA_kernel<<<dim3(NCHUNK, BD / 256), 256, 0, stream>>>(FG, U, av);
  scanB_kernel<<<BD / 256, 256, 0, stream>>>(av, c0, carries, out1);
  scanC_kernel<<<dim3(NCHUNK, BD / 256), 256, 0, stream>>>(
      FG, U, RG, xn, x, carries, out0);
}

// Round 3
// 231.821 us; speedup vs baseline: 1.1165x; 1.0422x over previous
//
#include <hip/hip_runtime.h>
#include <hip/hip_bf16.h>

// Problem dims (fixed by reference)
#define L_DIM 2048
#define B_DIM 8
#define D_DIM 1024
#define M_DIM (L_DIM * B_DIM)   // 16384 rows of x_norm
#define N_DIM (3 * D_DIM)       // 3072
#define K_DIM D_DIM             // 1024
#define BD (B_DIM * D_DIM)      // 8192 independent recurrence chains
#define NCHUNK 64
#define CLEN (L_DIM / NCHUNK)   // 32

typedef __attribute__((ext_vector_type(8))) __bf16 bf16x8;
typedef __attribute__((ext_vector_type(4))) __bf16 bf16x4;
typedef __attribute__((ext_vector_type(4))) float f32x4;

#define GLOAD_LDS16(g, l)                                        \
  __builtin_amdgcn_global_load_lds(                              \
      (const __attribute__((address_space(1))) void*)(g),        \
      (__attribute__((address_space(3))) void*)(l), 16, 0, 0)

__device__ __forceinline__ float sigmoidf_(float v) {
  return 1.0f / (1.0f + __expf(-v));
}

// ---------------------------------------------------------------------------
// Kernel 1: LayerNorm per (l,b) row of D=1024.
// ---------------------------------------------------------------------------
__global__ __launch_bounds__(256) void ln_kernel(
    const float* __restrict__ x, const float* __restrict__ gamma,
    const float* __restrict__ beta, __bf16* __restrict__ xn) {
  const int row = blockIdx.x;
  const int tid = threadIdx.x;
  const float4 v = ((const float4*)(x + (size_t)row * D_DIM))[tid];
  float s  = v.x + v.y + v.z + v.w;
  float ss = v.x * v.x + v.y * v.y + v.z * v.z + v.w * v.w;
  #pragma unroll
  for (int off = 32; off > 0; off >>= 1) {
    s  += __shfl_xor(s, off);
    ss += __shfl_xor(ss, off);
  }
  __shared__ float sb[8];
  const int wid = tid >> 6, lane = tid & 63;
  if (lane == 0) { sb[wid] = s; sb[4 + wid] = ss; }
  __syncthreads();
  const float tot  = sb[0] + sb[1] + sb[2] + sb[3];
  const float tot2 = sb[4] + sb[5] + sb[6] + sb[7];
  const float mu  = tot * (1.0f / D_DIM);
  const float var = tot2 * (1.0f / D_DIM) - mu * mu;
  const float rstd = rsqrtf(var + 1e-5f);
  const float4 g  = ((const float4*)gamma)[tid];
  const float4 bt = ((const float4*)beta)[tid];
  bf16x4 o;
  o[0] = (__bf16)((v.x - mu) * rstd * g.x + bt.x);
  o[1] = (__bf16)((v.y - mu) * rstd * g.y + bt.y);
  o[2] = (__bf16)((v.z - mu) * rstd * g.z + bt.z);
  o[3] = (__bf16)((v.w - mu) * rstd * g.w + bt.w);
  ((bf16x4*)(xn + (size_t)row * D_DIM))[tid] = o;
}

// ---------------------------------------------------------------------------
// Kernel 2: W fp32 -> bf16
// ---------------------------------------------------------------------------
__global__ __launch_bounds__(256) void wconv_kernel(
    const float* __restrict__ W, __bf16* __restrict__ Wb) {
  const size_t i = ((size_t)blockIdx.x * 256 + threadIdx.x) * 4;
  const float4 v = *(const float4*)(W + i);
  bf16x4 o;
  o[0] = (__bf16)v.x; o[1] = (__bf16)v.y; o[2] = (__bf16)v.z; o[3] = (__bf16)v.w;
  *(bf16x4*)(Wb + i) = o;
}

// ---------------------------------------------------------------------------
// Kernel 3: 256x256 GEMM, 4-phase counted-vmcnt pipeline.
//
// Stage unit = (op, half h, ks) = [128 rows][32 elems] 8 KB, staged by ALL
// 512 threads (1 gload_lds/thread): tid -> (row=tid>>2, slot=tid&3), global
// 16B-slot = slot ^ ((row>>1)&3)  (XOR on SOURCE, LDS linear; frag reads
// apply the same XOR -> bank-uniform; per instr global = 16 rows x 64B).
//
// Issue (tile t): P1: A-K1(t+1) x2h   P2: B-K1(t+1) x2h
//                 P3: A-K0(t+2) x2h   P4: B-K0(t+2) x2h
// Slot safety: A/B-K1 of buf(t+1) last read (t-1).P3/P4 (barriers between);
// A/B-K0 of buf(t) last read t.P1/P2, re-staged t.P3/P4 after P2-end barrier.
// Waits (2 loads/phase, 8/tile): P2-end vmcnt(8) -> K1(t) landed (issued
// (t-1).P1/P2, 8 newer); P4-end vmcnt(8) -> K0(t+1) landed. Tails:
// kt=14.P4 vmcnt(4); kt=15.P2 vmcnt(0); kt=15.P4 none.
// Prologue: tile0 all 8 units + tile1 K0 x4; vmcnt(4); barrier.
// Epilogue: acc -> LDS [128][264] bf16 (2 half-phases) -> dwordx4 stores.
// ---------------------------------------------------------------------------
#define VMCNT(n) asm volatile("s_waitcnt vmcnt(" #n ")" ::: "memory")

__global__ __launch_bounds__(512, 2) void gemm256_kernel(
    const __bf16* __restrict__ A,   // [M][K]
    const __bf16* __restrict__ Bm,  // [N][K]
    const float* __restrict__ bias,
    __bf16* __restrict__ U, __bf16* __restrict__ FG, __bf16* __restrict__ RG) {
  __shared__ __bf16 lds[65536];  // 128 KiB
  const int tid = threadIdx.x;
  const int lane = tid & 63;
  const int wid = tid >> 6;       // 0..7
  const int wm = wid >> 2;        // 0..1  (row-half)
  const int wn = wid & 3;         // 0..3  (col quarter)
  const int g2 = wn >> 1;         // B row-half this wave reads

  // XCD-bijective swizzle: 768 blocks, 768 % 8 == 0.
  const int bid0 = blockIdx.x;
  const int bid = (bid0 & 7) * 96 + (bid0 >> 3);
  const int bm = bid / 12, bn = bid % 12;

#define AUNIT(buf, h, ks) ((buf) * 32768 + (h) * 8192 + (ks) * 4096)
#define BUNIT(buf, h, ks) ((buf) * 32768 + 16384 + (h) * 8192 + (ks) * 4096)

  // Staging: one 16B load per thread per unit, coalesced 64B/row globally.
  const int srow  = tid >> 2;                       // 0..127
  const int sslot = (tid & 3) ^ ((srow >> 1) & 3);  // swizzled 16B slot
  auto stageA = [&](int kt2, int h, int ks) {
    const __bf16* gs = A + (size_t)(bm * 256 + h * 128 + srow) * K_DIM +
                       kt2 * 64 + ks * 32 + sslot * 8;
    GLOAD_LDS16(gs, lds + AUNIT(kt2 & 1, h, ks) + tid * 8);
  };
  auto stageB = [&](int kt2, int h, int ks) {
    const __bf16* gs = Bm + (size_t)(bn * 256 + h * 128 + srow) * K_DIM +
                       kt2 * 64 + ks * 32 + sslot * 8;
    GLOAD_LDS16(gs, lds + BUNIT(kt2 & 1, h, ks) + tid * 8);
  };

  const int fr = lane & 15, fk = lane >> 4;
  const int swz = fk ^ ((fr >> 1) & 3);             // undo source swizzle
  auto rdA = [&](int buf, int ks, int m) {
    return *(const bf16x8*)(lds + AUNIT(buf, wm, ks) + (m * 16 + fr) * 32 +
                            swz * 8);
  };
  auto rdB = [&](int buf, int ks, int n) {
    return *(const bf16x8*)(lds + BUNIT(buf, g2, ks) +
                            ((wn & 1) * 64 + n * 16 + fr) * 32 + swz * 8);
  };

  f32x4 acc[8][4] = {};

  // Prologue: tile0 all 8 units, tile1 K0 units (newest 4).
  stageA(0, 0, 0); stageA(0, 1, 0); stageB(0, 0, 0); stageB(0, 1, 0);
  stageA(0, 0, 1); stageA(0, 1, 1); stageB(0, 0, 1); stageB(0, 1, 1);
  stageA(1, 0, 0); stageA(1, 1, 0); stageB(1, 0, 0); stageB(1, 1, 0);
  VMCNT(4);
  __builtin_amdgcn_s_barrier();

  #pragma unroll 1
  for (int kt = 0; kt < 16; ++kt) {
    const int buf = kt & 1;
    bf16x8 a[4], b[4];

    // ---- P1: ks0, m 0-3 ----
    #pragma unroll
    for (int m = 0; m < 4; ++m) a[m] = rdA(buf, 0, m);
    #pragma unroll
    for (int n = 0; n < 4; ++n) b[n] = rdB(buf, 0, n);
    if (kt < 15) { stageA(kt + 1, 0, 1); stageA(kt + 1, 1, 1); }
    __builtin_amdgcn_s_barrier();
    __builtin_amdgcn_s_setprio(1);
    #pragma unroll
    for (int m = 0; m < 4; ++m)
      #pragma unroll
      for (int n = 0; n < 4; ++n)
        acc[m][n] = __builtin_amdgcn_mfma_f32_16x16x32_bf16(a[m], b[n],
                                                            acc[m][n], 0, 0, 0);
    __builtin_amdgcn_s_setprio(0);
    __builtin_amdgcn_s_barrier();

    // ---- P2: ks0, m 4-7 ----
    #pragma unroll
    for (int m = 0; m < 4; ++m) a[m] = rdA(buf, 0, m + 4);
    if (kt < 15) { stageB(kt + 1, 0, 1); stageB(kt + 1, 1, 1); }
    __builtin_amdgcn_s_barrier();
    __builtin_amdgcn_s_setprio(1);
    #pragma unroll
    for (int m = 0; m < 4; ++m)
      #pragma unroll
      for (int n = 0; n < 4; ++n)
        acc[m + 4][n] = __builtin_amdgcn_mfma_f32_16x16x32_bf16(
            a[m], b[n], acc[m + 4][n], 0, 0, 0);
    __builtin_amdgcn_s_setprio(0);
    if (kt == 15) { VMCNT(0); } else { VMCNT(8); }  // K1(kt) guaranteed
    __builtin_amdgcn_s_barrier();

    // ---- P3: ks1, m 0-3 ----
    #pragma unroll
    for (int m = 0; m < 4; ++m) a[m] = rdA(buf, 1, m);
    #pragma unroll
    for (int n = 0; n < 4; ++n) b[n] = rdB(buf, 1, n);
    if (kt < 14) { stageA(kt + 2, 0, 0); stageA(kt + 2, 1, 0); }
    __builtin_amdgcn_s_barrier();
    __builtin_amdgcn_s_setprio(1);
    #pragma unroll
    for (int m = 0; m < 4; ++m)
      #pragma unroll
      for (int n = 0; n < 4; ++n)
        acc[m][n] = __builtin_amdgcn_mfma_f32_16x16x32_bf16(a[m], b[n],
                                                            acc[m][n], 0, 0, 0);
    __builtin_amdgcn_s_setprio(0);
    __builtin_amdgcn_s_barrier();

    // ---- P4: ks1, m 4-7 ----
    #pragma unroll
    for (int m = 0; m < 4; ++m) a[m] = rdA(buf, 1, m + 4);
    if (kt < 14) { stageB(kt + 2, 0, 0); stageB(kt + 2, 1, 0); }
    __builtin_amdgcn_s_barrier();
    __builtin_amdgcn_s_setprio(1);
    #pragma unroll
    for (int m = 0; m < 4; ++m)
      #pragma unroll
      for (int n = 0; n < 4; ++n)
        acc[m + 4][n] = __builtin_amdgcn_mfma_f32_16x16x32_bf16(
            a[m], b[n], acc[m + 4][n], 0, 0, 0);
    __builtin_amdgcn_s_setprio(0);
    if (kt < 14) { VMCNT(8); }            // K0(kt+1) guaranteed
    else if (kt == 14) { VMCNT(4); }      // tail: only K1(15) in flight
    __builtin_amdgcn_s_barrier();
  }

  // Epilogue: acc -> LDS (bf16, [128 rows][264 cols], 2 half-phases) ->
  // coalesced dwordx4 stores. All staging loads drained (vmcnt(0) at 15.P2).
  const int seg = bn >> 2;  // 0:u 1:f 2:r
  __bf16* outb = (seg == 0) ? U : ((seg == 1) ? FG : RG);
  const int segcol0 = (bn & 3) * 256;

  float bv[4];
  #pragma unroll
  for (int n = 0; n < 4; ++n)
    bv[n] = bias[seg * 1024 + segcol0 + wn * 64 + n * 16 + fr];

  const int lrow = tid >> 5;        // 0..15 (readback)
  const int chunk = tid & 31;       // 16B chunk within 512B row
  #pragma unroll 1
  for (int h = 0; h < 2; ++h) {
    __syncthreads();
    if (wm == h) {
      #pragma unroll
      for (int m = 0; m < 8; ++m)
        #pragma unroll
        for (int n = 0; n < 4; ++n)
          #pragma unroll
          for (int j = 0; j < 4; ++j) {
            float v = acc[m][n][j] + bv[n];
            if (seg != 0) v = sigmoidf_(v);
            lds[(m * 16 + fk * 4 + j) * 264 + wn * 64 + n * 16 + fr] =
                (__bf16)v;
          }
    }
    __syncthreads();
    #pragma unroll
    for (int it = 0; it < 8; ++it) {
      const int r = it * 16 + lrow;
      const bf16x8 val = *(const bf16x8*)(lds + r * 264 + chunk * 8);
      const size_t grow = (size_t)(bm * 256 + h * 128 + r);
      *(bf16x8*)(outb + grow * D_DIM + segcol0 + chunk * 8) = val;
    }
  }
}

// ---------------------------------------------------------------------------
// Scan pass A: per (chunk, bd) affine composition over CLEN steps.
// ---------------------------------------------------------------------------
__global__ __launch_bounds__(256) void scanA_kernel(
    const __bf16* __restrict__ fg, const __bf16* __restrict__ u,
    float* __restrict__ av) {
  const int ci = blockIdx.x;
  const int bd = blockIdx.y * 256 + threadIdx.x;
  float a = 1.0f, v = 0.0f;
  const size_t base = (size_t)ci * CLEN * BD + bd;
  #pragma unroll 8
  for (int i = 0; i < CLEN; ++i) {
    const size_t idx = base + (size_t)i * BD;
    const float f = (float)fg[idx];
    const float uu = (float)u[idx];
    a *= f;
    v = f * v + (1.0f - f) * uu;
  }
  av[(size_t)ci * BD + bd] = a;
  av[(size_t)NCHUNK * BD + (size_t)ci * BD + bd] = v;
}

// ---------------------------------------------------------------------------
// Scan pass B: sequential combine across chunks; writes last_c.
// ---------------------------------------------------------------------------
__global__ __launch_bounds__(256) void scanB_kernel(
    const float* __restrict__ av, const float* __restrict__ c0,
    float* __restrict__ carries, float* __restrict__ out1) {
  const int bd = blockIdx.x * 256 + threadIdx.x;
  float c = c0[bd];
  #pragma unroll 8
  for (int ci = 0; ci < NCHUNK; ++ci) {
    carries[(size_t)ci * BD + bd] = c;
    c = av[(size_t)ci * BD + bd] * c + av[(size_t)NCHUNK * BD + (size_t)ci * BD + bd];
  }
  out1[bd] = c;
}

// ---------------------------------------------------------------------------
// Scan pass C: re-run recurrence within chunk, fuse hs + residual.
// ---------------------------------------------------------------------------
__global__ __launch_bounds__(256) void scanC_kernel(
    const __bf16* __restrict__ fg, const __bf16* __restrict__ u,
    const __bf16* __restrict__ rg, const __bf16* __restrict__ xn,
    const float* __restrict__ x, const float* __restrict__ carries,
    float* __restrict__ out0) {
  const int ci = blockIdx.x;
  const int bd = blockIdx.y * 256 + threadIdx.x;
  float c = carries[(size_t)ci * BD + bd];
  const size_t base = (size_t)ci * CLEN * BD + bd;
  #pragma unroll 4
  for (int i = 0; i < CLEN; ++i) {
    const size_t idx = base + (size_t)i * BD;
    const float f = (float)fg[idx];
    const float uu = (float)u[idx];
    c = f * c + (1.0f - f) * uu;
    const float r = (float)rg[idx];
    const float xnv = (float)xn[idx];
    const float hs = r * tanhf(c) + (1.0f - r) * xnv;
    out0[idx] = x[idx] + hs;
  }
}

// ---------------------------------------------------------------------------
extern "C" void kernel_launch(void* const* d_in, const int* in_sizes, int n_in,
                              void* d_out, int out_size, void* d_ws,
                              size_t ws_size, hipStream_t stream) {
  const float* x     = (const float*)d_in[0];
  const float* c0    = (const float*)d_in[1];
  const float* W     = (const float*)d_in[2];
  const float* bias  = (const float*)d_in[3];
  const float* gamma = (const float*)d_in[4];
  const float* beta  = (const float*)d_in[5];

  float* out0 = (float*)d_out;                 // [L,B,D]
  float* out1 = out0 + (size_t)M_DIM * D_DIM;  // [B,D]

  char* ws = (char*)d_ws;
  __bf16* xn = (__bf16*)(ws + 0);              // 32 MB
  __bf16* Wb = (__bf16*)(ws + 33554432);       //  6 MB
  __bf16* U  = (__bf16*)(ws + 39845888);       // 32 MB
  __bf16* FG = (__bf16*)(ws + 73400320);       // 32 MB
  __bf16* RG = (__bf16*)(ws + 106954752);      // 32 MB
  float* av      = (float*)(ws + 140509184);   //  4 MB
  float* carries = (float*)(ws + 144703488);   //  2 MB

  ln_kernel<<<M_DIM, 256, 0, stream>>>(x, gamma, beta, xn);
  wconv_kernel<<<(N_DIM * K_DIM / 4) / 256, 256, 0, stream>>>(W, Wb);
  gemm256_kernel<<<(M_DIM / 256) * (N_DIM / 256), 512, 0, stream>>>(
      xn, Wb, bias, U, FG, RG);
  scanA_kernel<<<dim3(NCHUNK, BD / 256), 256, 0, stream>>>(FG, U, av);
  scanB_kernel<<<BD / 256, 256, 0, stream>>>(av, c0, carries, out1);
  scanC_kernel<<<dim3(NCHUNK, BD / 256), 256, 0, stream>>>(
      FG, U, RG, xn, x, carries, out0);
}